// Round 3
// baseline (527.370 us; speedup 1.0000x reference)
//
#include <hip/hip_runtime.h>
#include <stdint.h>
#include <math.h>

// Problem constants (from reference)
#define NB 16
#define NK 16384
#define NADD 32
#define NP 36          // 2^RANK + ADD = 4 + 32
#define DIM 65536      // IN_DIM == OUT_DIM

__device__ __forceinline__ uint32_t rotl32(uint32_t x, uint32_t r) {
    return (x << r) | (x >> (32u - r));
}

// Threefry-2x32 (20 rounds), key = (0, 42)  [jax.random.key(42)]
// Partitionable-mode random bits: counter = (hi=0, lo=idx); bits = out0 ^ out1.
// CONFIRMED correct by round-1/2 absmax (only ulp-level sigmoid flips remain).
__device__ __forceinline__ uint32_t tf_bits(uint32_t idx) {
    const uint32_t K1 = 42u;
    const uint32_t K2 = 0x1BD11BDAu ^ 42u;  // k0 ^ k1 ^ C, k0 == 0
    uint32_t x0 = 0u;        // counts_hi(0) + k0(0)
    uint32_t x1 = idx + K1;  // counts_lo + k1
#define TF_ROUND(r) { x0 += x1; x1 = rotl32(x1, r); x1 ^= x0; }
#define TF_G(a,b,c,d) TF_ROUND(a) TF_ROUND(b) TF_ROUND(c) TF_ROUND(d)
    TF_G(13,15,26,6)   x0 += K1;  x1 += K2 + 1u;
    TF_G(17,29,16,24)  x0 += K2;  x1 += 2u;        // + k0(=0) + 2
    TF_G(13,15,26,6)              x1 += K1 + 3u;   // x0 += k0(=0)
    TF_G(17,29,16,24)  x0 += K1;  x1 += K2 + 4u;
    TF_G(13,15,26,6)   x0 += K2;  x1 += 5u;        // + k0(=0) + 5
#undef TF_G
#undef TF_ROUND
    return x0 ^ x1;
}

// Bit-exact replica of XLA:CPU's f32 exp (llvm_ir_runtime GenerateVF32Exp,
// the Cephes/Eigen pexp polynomial). Strict per-op IEEE f32 rounding, NO fma
// (JAX default xla_cpu_enable_fast_math=false -> no contraction). All ops use
// __f*_rn intrinsics so HIP's default -ffp-contract=fast cannot fuse them.
__device__ __forceinline__ float xla_expf(float x0) {
    float x = fminf(fmaxf(x0, -88.3762626647949f), 88.3762626647950f);
    const float fx = floorf(__fadd_rn(__fmul_rn(x, 1.44269504088896341f), 0.5f));
    const float tmp = __fmul_rn(fx, 0.693359375f);      // cephes_exp_C1
    float z = __fmul_rn(fx, -2.12194440e-4f);           // cephes_exp_C2
    float r = __fsub_rn(x, tmp);
    r = __fsub_rn(r, z);
    z = __fmul_rn(r, r);
    float y = 1.9875691500E-4f;                         // p0
    y = __fadd_rn(__fmul_rn(y, r), 1.3981999507E-3f);   // p1
    y = __fadd_rn(__fmul_rn(y, r), 8.3334519073E-3f);   // p2
    y = __fadd_rn(__fmul_rn(y, r), 4.1665795894E-2f);   // p3
    y = __fadd_rn(__fmul_rn(y, r), 1.6666665459E-1f);   // p4
    y = __fadd_rn(__fmul_rn(y, r), 5.0000001201E-1f);   // p5
    y = __fadd_rn(__fmul_rn(y, z), r);
    y = __fadd_rn(y, 1.0f);
    const int n = (int)fx;                              // fx clamped -> safe
    const float p2n = __uint_as_float((uint32_t)(n + 127) << 23);
    return fmaxf(__fmul_rn(y, p2n), x0);                // trailing max, inert here
}

// y[b, o] = bias[o] broadcast; one float4 per thread. 262144 threads.
__global__ __launch_bounds__(256) void init_bias_kernel(
    const float4* __restrict__ bias4, float4* __restrict__ y4)
{
    const int i = blockIdx.x * 256 + threadIdx.x;   // [0, NB*DIM/4)
    y4[i] = bias4[i & 16383];                       // DIM/4 = 16384 float4 per row
}

__global__ __launch_bounds__(256) void hyper_scatter(
    const float*  __restrict__ x,     // (NB, DIM)
    const float4* __restrict__ res4,  // (NB, NK, 4)
    float*        __restrict__ y)     // (NB, DIM)
{
    const int tid = blockIdx.x * 256 + threadIdx.x;   // == b*NK + k
    const int b = tid >> 14;                          // NK = 16384
    const float4 r = res4[tid];

    // sigmoid, XLA:CPU chain: logistic -> 1/(1+exp(-x)) with Cephes exp,
    // stepwise f32, contraction-proof. Only this chain feeds floor/ceil.
    const float e0 = xla_expf(-r.x);
    const float e1 = xla_expf(-r.y);
    const float s0 = __fdiv_rn(1.0f, __fadd_rn(1.0f, e0));
    const float s1 = __fdiv_rn(1.0f, __fadd_rn(1.0f, e1));
    const float m0 = __fmul_rn(s0, 65535.0f);
    const float m1 = __fmul_rn(s1, 65535.0f);

    // sigmas = (softplus(res[...,2] + 2) + 1e-6) * size  (smooth downstream ->
    // device-fast math is fine here)
    const float a2 = r.z + 2.0f;
    const float sp = fmaxf(a2, 0.0f) + log1pf(expf(-fabsf(a2)));
    const float sigma = (sp + 1e-6f) * 65536.0f;
    const float val = r.w;

    uint32_t packed[NP];   // (out_idx << 16) | in_idx ; both < 65536
    float    prop[NP];

    // 4 floor/ceil neighbors, mask order (T,T),(T,F),(F,T),(F,F), True=floor
    const float f0 = floorf(m0), c0 = ceilf(m0);
    const float f1 = floorf(m1), c1 = ceilf(m1);
    {
        const float cd0[4] = {f0, f0, c0, c0};
        const float cd1[4] = {f1, c1, f1, c1};
        #pragma unroll
        for (int p = 0; p < 4; ++p) {
            const float z0 = (cd0[p] - m0) / sigma;
            const float z1 = (cd1[p] - m1) / sigma;
            prop[p] = expf(-0.5f * (z0*z0 + z1*z1));
            packed[p] = ((uint32_t)(int)cd0[p] << 16) | (uint32_t)(int)cd1[p];
        }
    }

    // 32 sampled tuples: flat u-index base = ((b*NK + k)*NADD)*RANK = tid*64
    // Exact-arithmetic chain: bitcast, Sterbenz-exact sub, CR mul, exact *2^16,
    // floor. __fmul_rn prevents any contraction/reassociation.
    const float ONE_MEPS = (float)(1.0 - 1e-6);
    const uint32_t base = (uint32_t)tid * 64u;
    #pragma unroll
    for (int a = 0; a < NADD; ++a) {
        const uint32_t bb0 = tf_bits(base + 2u*(uint32_t)a);
        const uint32_t bb1 = tf_bits(base + 2u*(uint32_t)a + 1u);
        const float u0 = __fmul_rn(__uint_as_float((bb0 >> 9) | 0x3f800000u) - 1.0f, ONE_MEPS);
        const float u1 = __fmul_rn(__uint_as_float((bb1 >> 9) | 0x3f800000u) - 1.0f, ONE_MEPS);
        const float s0f = floorf(__fmul_rn(u0, 65536.0f));
        const float s1f = floorf(__fmul_rn(u1, 65536.0f));
        const float z0 = (s0f - m0) / sigma;
        const float z1 = (s1f - m1) / sigma;
        prop[4 + a] = expf(-0.5f * (z0*z0 + z1*z1));
        packed[4 + a] = ((uint32_t)(int)s0f << 16) | (uint32_t)(int)s1f;
    }

    // denom = sum_p (prop[p] + 1e-6)  (reference adds eps per element before sum)
    float denom = 0.0f;
    #pragma unroll
    for (int p = 0; p < NP; ++p) denom += prop[p] + 1e-6f;

    const float scale = val / denom;
    const float* __restrict__ xrow = x + ((size_t)b << 16);
    float*       __restrict__ yrow = y + ((size_t)b << 16);

    #pragma unroll
    for (int p = 0; p < NP; ++p) {
        const float xv = xrow[packed[p] & 0xFFFFu];
        unsafeAtomicAdd(&yrow[packed[p] >> 16], scale * prop[p] * xv);
    }
}

extern "C" void kernel_launch(void* const* d_in, const int* in_sizes, int n_in,
                              void* d_out, int out_size, void* d_ws, size_t ws_size,
                              hipStream_t stream) {
    const float*  x     = (const float*)d_in[0];   // (16, 65536) f32
    const float4* res4  = (const float4*)d_in[1];  // (16, 16384, 4) f32
    const float4* bias4 = (const float4*)d_in[2];  // (65536,) f32
    // d_in[3] (temp_indices) is dead: reference overwrites both template columns.
    float* y = (float*)d_out;                      // (16, 65536) f32

    init_bias_kernel<<<(NB * DIM / 4) / 256, 256, 0, stream>>>(bias4, (float4*)y);
    hyper_scatter<<<(NB * NK) / 256, 256, 0, stream>>>(x, res4, y);
}

// Round 4
// 190.793 us; speedup vs baseline: 2.7641x; 2.7641x over previous
//
#include <hip/hip_runtime.h>
#include <stdint.h>
#include <math.h>

// Problem constants (from reference)
#define NB 16
#define NK 16384
#define NADD 32
#define NP 36            // 2^RANK + ADD = 4 + 32
#define DIM 65536        // IN_DIM == OUT_DIM
#define NCH 4            // output chunks
#define CHW 16384        // chunk width (floats) -> 64 KB LDS accumulator
#define CAP 2816         // bucket capacity per (source block, chunk); mean 2304, +10 sigma
#define M2 16            // K2 blocks per (b, chunk); each covers 4 source blocks

__device__ __forceinline__ uint32_t rotl32(uint32_t x, uint32_t r) {
    return (x << r) | (x >> (32u - r));
}

// Threefry-2x32 (20 rounds), key = (0, 42); partitionable mode: ctr=(0,idx),
// bits = out0 ^ out1. CONFIRMED bit-correct (rounds 1-3).
__device__ __forceinline__ uint32_t tf_bits(uint32_t idx) {
    const uint32_t K1 = 42u;
    const uint32_t K2 = 0x1BD11BDAu ^ 42u;
    uint32_t x0 = 0u;
    uint32_t x1 = idx + K1;
#define TF_ROUND(r) { x0 += x1; x1 = rotl32(x1, r); x1 ^= x0; }
#define TF_G(a,b,c,d) TF_ROUND(a) TF_ROUND(b) TF_ROUND(c) TF_ROUND(d)
    TF_G(13,15,26,6)   x0 += K1;  x1 += K2 + 1u;
    TF_G(17,29,16,24)  x0 += K2;  x1 += 2u;
    TF_G(13,15,26,6)              x1 += K1 + 3u;
    TF_G(17,29,16,24)  x0 += K1;  x1 += K2 + 4u;
    TF_G(13,15,26,6)   x0 += K2;  x1 += 5u;
#undef TF_G
#undef TF_ROUND
    return x0 ^ x1;
}

// Bit-exact XLA:CPU f32 exp (Cephes/Eigen pexp), strict per-op f32 rounding,
// no FMA contraction. CONFIRMED: round 3 passed with absmax 7.8e-3.
__device__ __forceinline__ float xla_expf(float x0) {
    float x = fminf(fmaxf(x0, -88.3762626647949f), 88.3762626647950f);
    const float fx = floorf(__fadd_rn(__fmul_rn(x, 1.44269504088896341f), 0.5f));
    const float tmp = __fmul_rn(fx, 0.693359375f);
    float z = __fmul_rn(fx, -2.12194440e-4f);
    float r = __fsub_rn(x, tmp);
    r = __fsub_rn(r, z);
    z = __fmul_rn(r, r);
    float y = 1.9875691500E-4f;
    y = __fadd_rn(__fmul_rn(y, r), 1.3981999507E-3f);
    y = __fadd_rn(__fmul_rn(y, r), 8.3334519073E-3f);
    y = __fadd_rn(__fmul_rn(y, r), 4.1665795894E-2f);
    y = __fadd_rn(__fmul_rn(y, r), 1.6666665459E-1f);
    y = __fadd_rn(__fmul_rn(y, r), 5.0000001201E-1f);
    y = __fadd_rn(__fmul_rn(y, z), r);
    y = __fadd_rn(y, 1.0f);
    const int n = (int)fx;
    const float p2n = __uint_as_float((uint32_t)(n + 127) << 23);
    return fmaxf(__fmul_rn(y, p2n), x0);
}

// Shared generation: fills packed[36] ((out<<16)|in) and w[36] (normalized
// weight scale*prop). Identical arithmetic to the round-3 passing kernel.
__device__ __forceinline__ void gen_point(const float4 r, uint32_t tid,
                                          uint32_t* packed, float* w) {
    const float e0 = xla_expf(-r.x);
    const float e1 = xla_expf(-r.y);
    const float s0 = __fdiv_rn(1.0f, __fadd_rn(1.0f, e0));
    const float s1 = __fdiv_rn(1.0f, __fadd_rn(1.0f, e1));
    const float m0 = __fmul_rn(s0, 65535.0f);
    const float m1 = __fmul_rn(s1, 65535.0f);

    const float a2 = r.z + 2.0f;
    const float sp = fmaxf(a2, 0.0f) + log1pf(expf(-fabsf(a2)));
    const float sigma = (sp + 1e-6f) * 65536.0f;
    const float val = r.w;

    float prop[NP];
    const float f0 = floorf(m0), c0 = ceilf(m0);
    const float f1 = floorf(m1), c1 = ceilf(m1);
    {
        const float cd0[4] = {f0, f0, c0, c0};
        const float cd1[4] = {f1, c1, f1, c1};
        #pragma unroll
        for (int p = 0; p < 4; ++p) {
            const float z0 = (cd0[p] - m0) / sigma;
            const float z1 = (cd1[p] - m1) / sigma;
            prop[p] = expf(-0.5f * (z0*z0 + z1*z1));
            packed[p] = ((uint32_t)(int)cd0[p] << 16) | (uint32_t)(int)cd1[p];
        }
    }
    const float ONE_MEPS = (float)(1.0 - 1e-6);
    const uint32_t base = tid * 64u;
    #pragma unroll
    for (int a = 0; a < NADD; ++a) {
        const uint32_t bb0 = tf_bits(base + 2u*(uint32_t)a);
        const uint32_t bb1 = tf_bits(base + 2u*(uint32_t)a + 1u);
        const float u0 = __fmul_rn(__uint_as_float((bb0 >> 9) | 0x3f800000u) - 1.0f, ONE_MEPS);
        const float u1 = __fmul_rn(__uint_as_float((bb1 >> 9) | 0x3f800000u) - 1.0f, ONE_MEPS);
        const float s0f = floorf(__fmul_rn(u0, 65536.0f));
        const float s1f = floorf(__fmul_rn(u1, 65536.0f));
        const float z0 = (s0f - m0) / sigma;
        const float z1 = (s1f - m1) / sigma;
        prop[4 + a] = expf(-0.5f * (z0*z0 + z1*z1));
        packed[4 + a] = ((uint32_t)(int)s0f << 16) | (uint32_t)(int)s1f;
    }
    float denom = 0.0f;
    #pragma unroll
    for (int p = 0; p < NP; ++p) denom += prop[p] + 1e-6f;
    const float scale = val / denom;
    #pragma unroll
    for (int p = 0; p < NP; ++p) w[p] = scale * prop[p];
}

// ---------------- fast path: 3-kernel, zero global atomics ----------------

// K1: generate + bin candidates into per-(block,chunk) bucket lists.
__global__ __launch_bounds__(256) void k1_gen_bin(
    const float4* __restrict__ res4,
    unsigned long long* __restrict__ glist,   // [blk][chunk][CAP] items
    uint32_t* __restrict__ counts)            // [blk][chunk]
{
    __shared__ uint32_t cnt[NCH];
    const int blk = blockIdx.x;                       // = b*64 + src
    const int tid = blk * 256 + threadIdx.x;          // = b*NK + k
    if (threadIdx.x < NCH) cnt[threadIdx.x] = 0;
    __syncthreads();

    uint32_t packed[NP];
    float    w[NP];
    gen_point(res4[tid], (uint32_t)tid, packed, w);

    #pragma unroll
    for (int p = 0; p < NP; ++p) {
        const uint32_t pk = packed[p];
        const uint32_t c = pk >> 30;                  // out>>14
        const uint32_t rank = atomicAdd(&cnt[c], 1u);
        if (rank < CAP) {
            const size_t slot = (size_t)(blk * NCH + c) * CAP + rank;
            glist[slot] = ((unsigned long long)__float_as_uint(w[p]) << 32) | pk;
        }
    }
    __syncthreads();
    if (threadIdx.x < NCH)
        counts[blk * NCH + threadIdx.x] = min(cnt[threadIdx.x], (uint32_t)CAP);
}

// K2: per (b, chunk, m): stream 4 source buckets, gather x, LDS-accumulate,
// store a private partial chunk (no global atomics, no pre-zero needed).
__global__ __launch_bounds__(256) void k2_reduce(
    const float* __restrict__ x,
    const unsigned long long* __restrict__ glist,
    const uint32_t* __restrict__ counts,
    float* __restrict__ part)                 // [M2][NB][DIM]
{
    __shared__ float acc[CHW];                // 64 KB
    const int blk = blockIdx.x;               // b=blk>>6, c=(blk>>4)&3, m=blk&15
    const int b = blk >> 6;
    const int c = (blk >> 4) & 3;
    const int m = blk & 15;

    for (int j = threadIdx.x; j < CHW; j += 256) acc[j] = 0.0f;
    __syncthreads();

    const float* __restrict__ xrow = x + ((size_t)b << 16);
    #pragma unroll
    for (int s = 0; s < 4; ++s) {
        const int src = m * 4 + s;
        const int bucket = (b * 64 + src) * NCH + c;
        const uint32_t n = counts[bucket];
        const unsigned long long* __restrict__ base = glist + (size_t)bucket * CAP;
        for (uint32_t i = threadIdx.x; i < n; i += 256) {
            const unsigned long long it = base[i];
            const uint32_t pk = (uint32_t)it;
            const float wv = __uint_as_float((uint32_t)(it >> 32));
            const float xv = xrow[pk & 0xFFFFu];
            atomicAdd(&acc[(pk >> 16) & (CHW - 1)], wv * xv);
        }
    }
    __syncthreads();
    float* __restrict__ dst = part + (((size_t)m * NB + b) << 16) + (size_t)c * CHW;
    for (int j = threadIdx.x; j < CHW; j += 256) dst[j] = acc[j];
}

// K3: y = bias + sum_m part[m]; fully coalesced float4.
__global__ __launch_bounds__(256) void k3_final(
    const float4* __restrict__ part4,
    const float4* __restrict__ bias4,
    float4* __restrict__ y4)
{
    const int i = blockIdx.x * 256 + threadIdx.x;  // [0, NB*DIM/4)
    const int o4 = i & 16383;
    const int b = i >> 14;
    float4 s = bias4[o4];
    #pragma unroll
    for (int m = 0; m < M2; ++m) {
        const float4 p = part4[(((size_t)m * NB + b) << 14) + o4];
        s.x += p.x; s.y += p.y; s.z += p.z; s.w += p.w;
    }
    y4[i] = s;
}

// ---------------- fallback path (round-3 passing kernel) ----------------

__global__ __launch_bounds__(256) void init_bias_kernel(
    const float4* __restrict__ bias4, float4* __restrict__ y4)
{
    const int i = blockIdx.x * 256 + threadIdx.x;
    y4[i] = bias4[i & 16383];
}

__global__ __launch_bounds__(256) void hyper_scatter(
    const float*  __restrict__ x,
    const float4* __restrict__ res4,
    float*        __restrict__ y)
{
    const int tid = blockIdx.x * 256 + threadIdx.x;
    const int b = tid >> 14;
    uint32_t packed[NP];
    float    w[NP];
    gen_point(res4[tid], (uint32_t)tid, packed, w);
    const float* __restrict__ xrow = x + ((size_t)b << 16);
    float*       __restrict__ yrow = y + ((size_t)b << 16);
    #pragma unroll
    for (int p = 0; p < NP; ++p) {
        const float xv = xrow[packed[p] & 0xFFFFu];
        unsafeAtomicAdd(&yrow[packed[p] >> 16], w[p] * xv);
    }
}

extern "C" void kernel_launch(void* const* d_in, const int* in_sizes, int n_in,
                              void* d_out, int out_size, void* d_ws, size_t ws_size,
                              hipStream_t stream) {
    const float*  x     = (const float*)d_in[0];   // (16, 65536) f32
    const float4* res4  = (const float4*)d_in[1];  // (16, 16384, 4) f32
    const float4* bias4 = (const float4*)d_in[2];  // (65536,) f32
    float* y = (float*)d_out;                      // (16, 65536) f32

    // ws carve (256B-aligned)
    const size_t glist_bytes  = (size_t)NB * 64 * NCH * CAP * 8;      // ~92.3 MB
    const size_t counts_bytes = (size_t)NB * 64 * NCH * 4;            // 16 KB
    const size_t part_bytes   = (size_t)M2 * NB * DIM * 4;            // 64 MB
    const size_t off_counts = (glist_bytes + 255) & ~(size_t)255;
    const size_t off_part   = (off_counts + counts_bytes + 255) & ~(size_t)255;
    const size_t need = off_part + part_bytes;

    if (ws_size >= need) {
        unsigned long long* glist = (unsigned long long*)d_ws;
        uint32_t* counts = (uint32_t*)((char*)d_ws + off_counts);
        float* part = (float*)((char*)d_ws + off_part);
        k1_gen_bin<<<NB * 64, 256, 0, stream>>>(res4, glist, counts);
        k2_reduce<<<NB * NCH * M2, 256, 0, stream>>>(x, glist, counts, part);
        k3_final<<<(NB * DIM / 4) / 256, 256, 0, stream>>>((const float4*)part, bias4, (float4*)y);
    } else {
        // ws too small for binning: round-3 atomic path
        init_bias_kernel<<<(NB * DIM / 4) / 256, 256, 0, stream>>>(bias4, (float4*)y);
        hyper_scatter<<<(NB * NK) / 256, 256, 0, stream>>>(x, res4, y);
    }
}

// Round 5
// 178.187 us; speedup vs baseline: 2.9597x; 1.0707x over previous
//
#include <hip/hip_runtime.h>
#include <stdint.h>
#include <math.h>

// Problem constants (from reference)
#define NB 16
#define NK 16384
#define NADD 32
#define NP 36            // 2^RANK + ADD = 4 + 32
#define DIM 65536        // IN_DIM == OUT_DIM
#define NCH 4            // output chunks per batch row
#define CHW 16384        // chunk width (floats) -> 64 KB LDS accumulator
#define GPB 16           // point-groups per batch row (NK / 1024)

__device__ __forceinline__ uint32_t rotl32(uint32_t x, uint32_t r) {
    return (x << r) | (x >> (32u - r));
}

// Threefry-2x32 (20 rounds), key = (0, 42); partitionable mode: ctr=(0,idx),
// bits = out0 ^ out1. CONFIRMED bit-correct (rounds 1-4).
__device__ __forceinline__ uint32_t tf_bits(uint32_t idx) {
    const uint32_t K1 = 42u;
    const uint32_t K2 = 0x1BD11BDAu ^ 42u;
    uint32_t x0 = 0u;
    uint32_t x1 = idx + K1;
#define TF_ROUND(r) { x0 += x1; x1 = rotl32(x1, r); x1 ^= x0; }
#define TF_G(a,b,c,d) TF_ROUND(a) TF_ROUND(b) TF_ROUND(c) TF_ROUND(d)
    TF_G(13,15,26,6)   x0 += K1;  x1 += K2 + 1u;
    TF_G(17,29,16,24)  x0 += K2;  x1 += 2u;
    TF_G(13,15,26,6)              x1 += K1 + 3u;
    TF_G(17,29,16,24)  x0 += K1;  x1 += K2 + 4u;
    TF_G(13,15,26,6)   x0 += K2;  x1 += 5u;
#undef TF_G
#undef TF_ROUND
    return x0 ^ x1;
}

// Bit-exact XLA:CPU f32 exp (Cephes/Eigen pexp), strict per-op f32 rounding,
// no FMA contraction. CONFIRMED: rounds 3-4 passed with absmax 7.8e-3.
__device__ __forceinline__ float xla_expf(float x0) {
    float x = fminf(fmaxf(x0, -88.3762626647949f), 88.3762626647950f);
    const float fx = floorf(__fadd_rn(__fmul_rn(x, 1.44269504088896341f), 0.5f));
    const float tmp = __fmul_rn(fx, 0.693359375f);
    float z = __fmul_rn(fx, -2.12194440e-4f);
    float r = __fsub_rn(x, tmp);
    r = __fsub_rn(r, z);
    z = __fmul_rn(r, r);
    float y = 1.9875691500E-4f;
    y = __fadd_rn(__fmul_rn(y, r), 1.3981999507E-3f);
    y = __fadd_rn(__fmul_rn(y, r), 8.3334519073E-3f);
    y = __fadd_rn(__fmul_rn(y, r), 4.1665795894E-2f);
    y = __fadd_rn(__fmul_rn(y, r), 1.6666665459E-1f);
    y = __fadd_rn(__fmul_rn(y, r), 5.0000001201E-1f);
    y = __fadd_rn(__fmul_rn(y, z), r);
    y = __fadd_rn(y, 1.0f);
    const int n = (int)fx;
    const float p2n = __uint_as_float((uint32_t)(n + 127) << 23);
    return fmaxf(__fmul_rn(y, p2n), x0);
}

// Shared generation: fills packed[36] ((out<<16)|in) and w[36] (normalized
// weight scale*prop). Identical arithmetic to the round-3/4 passing kernels.
__device__ __forceinline__ void gen_point(const float4 r, uint32_t tid,
                                          uint32_t* packed, float* w) {
    const float e0 = xla_expf(-r.x);
    const float e1 = xla_expf(-r.y);
    const float s0 = __fdiv_rn(1.0f, __fadd_rn(1.0f, e0));
    const float s1 = __fdiv_rn(1.0f, __fadd_rn(1.0f, e1));
    const float m0 = __fmul_rn(s0, 65535.0f);
    const float m1 = __fmul_rn(s1, 65535.0f);

    const float a2 = r.z + 2.0f;
    const float sp = fmaxf(a2, 0.0f) + log1pf(expf(-fabsf(a2)));
    const float sigma = (sp + 1e-6f) * 65536.0f;
    const float val = r.w;

    const float f0 = floorf(m0), c0 = ceilf(m0);
    const float f1 = floorf(m1), c1 = ceilf(m1);
    {
        const float cd0[4] = {f0, f0, c0, c0};
        const float cd1[4] = {f1, c1, f1, c1};
        #pragma unroll
        for (int p = 0; p < 4; ++p) {
            const float z0 = (cd0[p] - m0) / sigma;
            const float z1 = (cd1[p] - m1) / sigma;
            w[p] = expf(-0.5f * (z0*z0 + z1*z1));
            packed[p] = ((uint32_t)(int)cd0[p] << 16) | (uint32_t)(int)cd1[p];
        }
    }
    const float ONE_MEPS = (float)(1.0 - 1e-6);
    const uint32_t base = tid * 64u;
    #pragma unroll
    for (int a = 0; a < NADD; ++a) {
        const uint32_t bb0 = tf_bits(base + 2u*(uint32_t)a);
        const uint32_t bb1 = tf_bits(base + 2u*(uint32_t)a + 1u);
        const float u0 = __fmul_rn(__uint_as_float((bb0 >> 9) | 0x3f800000u) - 1.0f, ONE_MEPS);
        const float u1 = __fmul_rn(__uint_as_float((bb1 >> 9) | 0x3f800000u) - 1.0f, ONE_MEPS);
        const float s0f = floorf(__fmul_rn(u0, 65536.0f));
        const float s1f = floorf(__fmul_rn(u1, 65536.0f));
        const float z0 = (s0f - m0) / sigma;
        const float z1 = (s1f - m1) / sigma;
        w[4 + a] = expf(-0.5f * (z0*z0 + z1*z1));
        packed[4 + a] = ((uint32_t)(int)s0f << 16) | (uint32_t)(int)s1f;
    }
    float denom = 0.0f;
    #pragma unroll
    for (int p = 0; p < NP; ++p) denom += w[p] + 1e-6f;
    const float scale = val / denom;
    #pragma unroll
    for (int p = 0; p < NP; ++p) w[p] *= scale;
}

// ---------------- fast path: fused gen+reduce, then coalesced sum ----------

// F1: 256 blocks x 1024 threads. Block (b,g) owns points [g*1024, g*1024+1024)
// of batch b. Generate in registers, fold x-gather into weights, then 4 LDS
// accumulation passes (one 64 KB chunk at a time) -> coalesced partial store.
// No global atomics, no candidate-list round-trip.
__global__ __launch_bounds__(1024) void f1_gen_reduce(
    const float*  __restrict__ x,     // (NB, DIM)
    const float4* __restrict__ res4,  // (NB, NK, 4)
    float* __restrict__ part)         // [NB*GPB][DIM]
{
    __shared__ float acc[CHW];        // 64 KB
    const int blk = blockIdx.x;       // = b*GPB + g
    const int b = blk >> 4;
    const uint32_t tid = (uint32_t)blk * 1024u + threadIdx.x;  // global point id

    uint32_t packed[NP];
    float    w[NP];
    gen_point(res4[tid], tid, packed, w);

    // fold gather: w[p] <- w[p] * x[b, in_idx]  (random 4B loads, L2-resident)
    const float* __restrict__ xrow = x + ((size_t)b << 16);
    #pragma unroll
    for (int p = 0; p < NP; ++p) w[p] *= xrow[packed[p] & 0xFFFFu];

    float* __restrict__ dst = part + ((size_t)blk << 16);
    #pragma unroll 1
    for (int c = 0; c < NCH; ++c) {
        for (int j = threadIdx.x; j < CHW; j += 1024) acc[j] = 0.0f;
        __syncthreads();
        #pragma unroll
        for (int p = 0; p < NP; ++p) {
            if ((packed[p] >> 30) == (uint32_t)c)
                atomicAdd(&acc[(packed[p] >> 16) & (CHW - 1)], w[p]);
        }
        __syncthreads();
        for (int j = threadIdx.x; j < CHW; j += 1024) dst[c * CHW + j] = acc[j];
        __syncthreads();   // protect acc from next pass's zeroing
    }
}

// F2: y = bias + sum_g part[(b*GPB+g)]; fully coalesced float4.
__global__ __launch_bounds__(256) void f2_final(
    const float4* __restrict__ part4,
    const float4* __restrict__ bias4,
    float4* __restrict__ y4)
{
    const int i = blockIdx.x * 256 + threadIdx.x;  // [0, NB*DIM/4)
    const int o4 = i & 16383;
    const int b = i >> 14;
    float4 s = bias4[o4];
    #pragma unroll
    for (int g = 0; g < GPB; ++g) {
        const float4 p = part4[(((size_t)(b * GPB + g)) << 14) + o4];
        s.x += p.x; s.y += p.y; s.z += p.z; s.w += p.w;
    }
    y4[i] = s;
}

// ---------------- fallback path (round-3 passing kernel) ----------------

__global__ __launch_bounds__(256) void init_bias_kernel(
    const float4* __restrict__ bias4, float4* __restrict__ y4)
{
    const int i = blockIdx.x * 256 + threadIdx.x;
    y4[i] = bias4[i & 16383];
}

__global__ __launch_bounds__(256) void hyper_scatter(
    const float*  __restrict__ x,
    const float4* __restrict__ res4,
    float*        __restrict__ y)
{
    const int tid = blockIdx.x * 256 + threadIdx.x;
    const int b = tid >> 14;
    uint32_t packed[NP];
    float    w[NP];
    gen_point(res4[tid], (uint32_t)tid, packed, w);
    const float* __restrict__ xrow = x + ((size_t)b << 16);
    float*       __restrict__ yrow = y + ((size_t)b << 16);
    #pragma unroll
    for (int p = 0; p < NP; ++p) {
        const float xv = xrow[packed[p] & 0xFFFFu];
        unsafeAtomicAdd(&yrow[packed[p] >> 16], w[p] * xv);
    }
}

extern "C" void kernel_launch(void* const* d_in, const int* in_sizes, int n_in,
                              void* d_out, int out_size, void* d_ws, size_t ws_size,
                              hipStream_t stream) {
    const float*  x     = (const float*)d_in[0];   // (16, 65536) f32
    const float4* res4  = (const float4*)d_in[1];  // (16, 16384, 4) f32
    const float4* bias4 = (const float4*)d_in[2];  // (65536,) f32
    float* y = (float*)d_out;                      // (16, 65536) f32

    const size_t part_bytes = (size_t)NB * GPB * DIM * 4;   // 64 MB

    if (ws_size >= part_bytes) {
        float* part = (float*)d_ws;
        f1_gen_reduce<<<NB * GPB, 1024, 0, stream>>>(x, res4, part);
        f2_final<<<(NB * DIM / 4) / 256, 256, 0, stream>>>((const float4*)part, bias4, (float4*)y);
    } else {
        // ws too small for partials: round-3 atomic path
        init_bias_kernel<<<(NB * DIM / 4) / 256, 256, 0, stream>>>(bias4, (float4*)y);
        hyper_scatter<<<(NB * NK) / 256, 256, 0, stream>>>(x, res4, y);
    }
}

// Round 7
// 176.143 us; speedup vs baseline: 2.9940x; 1.0116x over previous
//
#include <hip/hip_runtime.h>
#include <stdint.h>
#include <math.h>

// Problem constants (from reference)
#define NB 16
#define NK 16384
#define NADD 32
#define NP 36            // 2^RANK + ADD = 4 + 32
#define DIM 65536        // IN_DIM == OUT_DIM
#define NCH 4            // output chunks per batch row
#define CHW 16384        // chunk width (floats) -> 64 KB LDS accumulator
#define GPB 16           // point-groups per batch row (NK / 1024)

// native vector type for nontemporal builtins (HIP_vector_type rejected)
typedef float f32x4 __attribute__((ext_vector_type(4)));

__device__ __forceinline__ uint32_t rotl32(uint32_t x, uint32_t r) {
    return (x << r) | (x >> (32u - r));
}

// Threefry-2x32 (20 rounds), key = (0, 42); partitionable mode: ctr=(0,idx),
// bits = out0 ^ out1. CONFIRMED bit-correct (rounds 1-5).
__device__ __forceinline__ uint32_t tf_bits(uint32_t idx) {
    const uint32_t K1 = 42u;
    const uint32_t K2 = 0x1BD11BDAu ^ 42u;
    uint32_t x0 = 0u;
    uint32_t x1 = idx + K1;
#define TF_ROUND(r) { x0 += x1; x1 = rotl32(x1, r); x1 ^= x0; }
#define TF_G(a,b,c,d) TF_ROUND(a) TF_ROUND(b) TF_ROUND(c) TF_ROUND(d)
    TF_G(13,15,26,6)   x0 += K1;  x1 += K2 + 1u;
    TF_G(17,29,16,24)  x0 += K2;  x1 += 2u;
    TF_G(13,15,26,6)              x1 += K1 + 3u;
    TF_G(17,29,16,24)  x0 += K1;  x1 += K2 + 4u;
    TF_G(13,15,26,6)   x0 += K2;  x1 += 5u;
#undef TF_G
#undef TF_ROUND
    return x0 ^ x1;
}

// Bit-exact XLA:CPU f32 exp (Cephes/Eigen pexp), strict per-op f32 rounding,
// no FMA contraction. CONFIRMED: rounds 3-5 passed with absmax 7.8e-3.
__device__ __forceinline__ float xla_expf(float x0) {
    float x = fminf(fmaxf(x0, -88.3762626647949f), 88.3762626647950f);
    const float fx = floorf(__fadd_rn(__fmul_rn(x, 1.44269504088896341f), 0.5f));
    const float tmp = __fmul_rn(fx, 0.693359375f);
    float z = __fmul_rn(fx, -2.12194440e-4f);
    float r = __fsub_rn(x, tmp);
    r = __fsub_rn(r, z);
    z = __fmul_rn(r, r);
    float y = 1.9875691500E-4f;
    y = __fadd_rn(__fmul_rn(y, r), 1.3981999507E-3f);
    y = __fadd_rn(__fmul_rn(y, r), 8.3334519073E-3f);
    y = __fadd_rn(__fmul_rn(y, r), 4.1665795894E-2f);
    y = __fadd_rn(__fmul_rn(y, r), 1.6666665459E-1f);
    y = __fadd_rn(__fmul_rn(y, r), 5.0000001201E-1f);
    y = __fadd_rn(__fmul_rn(y, z), r);
    y = __fadd_rn(y, 1.0f);
    const int n = (int)fx;
    const float p2n = __uint_as_float((uint32_t)(n + 127) << 23);
    return fmaxf(__fmul_rn(y, p2n), x0);
}

// Shared generation: fills packed[36] ((out<<16)|in) and w[36] (normalized
// weight scale*prop). Identical arithmetic to the round-3/4/5 passing kernels.
__device__ __forceinline__ void gen_point(const float4 r, uint32_t tid,
                                          uint32_t* packed, float* w) {
    const float e0 = xla_expf(-r.x);
    const float e1 = xla_expf(-r.y);
    const float s0 = __fdiv_rn(1.0f, __fadd_rn(1.0f, e0));
    const float s1 = __fdiv_rn(1.0f, __fadd_rn(1.0f, e1));
    const float m0 = __fmul_rn(s0, 65535.0f);
    const float m1 = __fmul_rn(s1, 65535.0f);

    const float a2 = r.z + 2.0f;
    const float sp = fmaxf(a2, 0.0f) + log1pf(expf(-fabsf(a2)));
    const float sigma = (sp + 1e-6f) * 65536.0f;
    const float val = r.w;

    const float f0 = floorf(m0), c0 = ceilf(m0);
    const float f1 = floorf(m1), c1 = ceilf(m1);
    {
        const float cd0[4] = {f0, f0, c0, c0};
        const float cd1[4] = {f1, c1, f1, c1};
        #pragma unroll
        for (int p = 0; p < 4; ++p) {
            const float z0 = (cd0[p] - m0) / sigma;
            const float z1 = (cd1[p] - m1) / sigma;
            w[p] = expf(-0.5f * (z0*z0 + z1*z1));
            packed[p] = ((uint32_t)(int)cd0[p] << 16) | (uint32_t)(int)cd1[p];
        }
    }
    const float ONE_MEPS = (float)(1.0 - 1e-6);
    const uint32_t base = tid * 64u;
    #pragma unroll
    for (int a = 0; a < NADD; ++a) {
        const uint32_t bb0 = tf_bits(base + 2u*(uint32_t)a);
        const uint32_t bb1 = tf_bits(base + 2u*(uint32_t)a + 1u);
        const float u0 = __fmul_rn(__uint_as_float((bb0 >> 9) | 0x3f800000u) - 1.0f, ONE_MEPS);
        const float u1 = __fmul_rn(__uint_as_float((bb1 >> 9) | 0x3f800000u) - 1.0f, ONE_MEPS);
        const float s0f = floorf(__fmul_rn(u0, 65536.0f));
        const float s1f = floorf(__fmul_rn(u1, 65536.0f));
        const float z0 = (s0f - m0) / sigma;
        const float z1 = (s1f - m1) / sigma;
        w[4 + a] = expf(-0.5f * (z0*z0 + z1*z1));
        packed[4 + a] = ((uint32_t)(int)s0f << 16) | (uint32_t)(int)s1f;
    }
    float denom = 0.0f;
    #pragma unroll
    for (int p = 0; p < NP; ++p) denom += w[p] + 1e-6f;
    const float scale = val / denom;
    #pragma unroll
    for (int p = 0; p < NP; ++p) w[p] *= scale;
}

// ---------------- fast path: fused gen+reduce, then coalesced sum ----------

// F1: 256 blocks x 1024 threads. Block (b,g) owns points [g*1024, g*1024+1024)
// of batch b. Generate in registers, fold x-gather into weights, pre-pack
// scatter keys (sc = out<<2: chunk = sc>>16, lds word idx = (sc&0xFFFF)>>2),
// then 4 LDS accumulation passes with vectorized zero/store.
__global__ __launch_bounds__(1024) void f1_gen_reduce(
    const float*  __restrict__ x,     // (NB, DIM)
    const float4* __restrict__ res4,  // (NB, NK, 4)
    float* __restrict__ part)         // [NB*GPB][DIM]
{
    __shared__ float acc[CHW];        // 64 KB
    f32x4* const acc4 = reinterpret_cast<f32x4*>(acc);
    const int blk = blockIdx.x;       // = b*GPB + g
    const int b = blk >> 4;
    const uint32_t tid = (uint32_t)blk * 1024u + threadIdx.x;  // global point id

    uint32_t packed[NP];
    float    w[NP];
    gen_point(res4[tid], tid, packed, w);

    // fold gather: w[p] <- w[p] * x[b, in_idx]; then repack to scatter key.
    const float* __restrict__ xrow = x + ((size_t)b << 16);
    #pragma unroll
    for (int p = 0; p < NP; ++p) {
        w[p] *= xrow[packed[p] & 0xFFFFu];
        packed[p] = (packed[p] >> 16) << 2;   // sc = out*4
    }

    float* __restrict__ dst = part + ((size_t)blk << 16);
    #pragma unroll 1
    for (uint32_t c = 0; c < NCH; ++c) {
        // vectorized zero: 4096 f32x4 / 1024 threads = 4 iters
        #pragma unroll
        for (int j = 0; j < 4; ++j)
            acc4[j * 1024 + threadIdx.x] = (f32x4)(0.0f);
        __syncthreads();
        #pragma unroll
        for (int p = 0; p < NP; ++p) {
            if ((packed[p] >> 16) == c)
                atomicAdd(&acc[(packed[p] & 0xFFFFu) >> 2], w[p]);
        }
        __syncthreads();
        // vectorized nontemporal store (64 MB stream, read once by f2)
        f32x4* __restrict__ dst4 = reinterpret_cast<f32x4*>(dst + c * CHW);
        #pragma unroll
        for (int j = 0; j < 4; ++j)
            __builtin_nontemporal_store(acc4[j * 1024 + threadIdx.x],
                                        &dst4[j * 1024 + threadIdx.x]);
        __syncthreads();   // protect acc from next pass's zeroing
    }
}

// F2: y = bias + sum_g part[(b*GPB+g)]; fully coalesced f32x4, nontemporal.
__global__ __launch_bounds__(256) void f2_final(
    const f32x4* __restrict__ part4,
    const f32x4* __restrict__ bias4,
    f32x4* __restrict__ y4)
{
    const int i = blockIdx.x * 256 + threadIdx.x;  // [0, NB*DIM/4)
    const int o4 = i & 16383;
    const int b = i >> 14;
    f32x4 s = bias4[o4];
    #pragma unroll
    for (int g = 0; g < GPB; ++g) {
        const f32x4 p = __builtin_nontemporal_load(
            &part4[(((size_t)(b * GPB + g)) << 14) + o4]);
        s += p;
    }
    __builtin_nontemporal_store(s, &y4[i]);
}

// ---------------- fallback path (round-3 passing kernel) ----------------

__global__ __launch_bounds__(256) void init_bias_kernel(
    const float4* __restrict__ bias4, float4* __restrict__ y4)
{
    const int i = blockIdx.x * 256 + threadIdx.x;
    y4[i] = bias4[i & 16383];
}

__global__ __launch_bounds__(256) void hyper_scatter(
    const float*  __restrict__ x,
    const float4* __restrict__ res4,
    float*        __restrict__ y)
{
    const int tid = blockIdx.x * 256 + threadIdx.x;
    const int b = tid >> 14;
    uint32_t packed[NP];
    float    w[NP];
    gen_point(res4[tid], (uint32_t)tid, packed, w);
    const float* __restrict__ xrow = x + ((size_t)b << 16);
    float*       __restrict__ yrow = y + ((size_t)b << 16);
    #pragma unroll
    for (int p = 0; p < NP; ++p) {
        const float xv = xrow[packed[p] & 0xFFFFu];
        unsafeAtomicAdd(&yrow[packed[p] >> 16], w[p] * xv);
    }
}

extern "C" void kernel_launch(void* const* d_in, const int* in_sizes, int n_in,
                              void* d_out, int out_size, void* d_ws, size_t ws_size,
                              hipStream_t stream) {
    const float*  x     = (const float*)d_in[0];   // (16, 65536) f32
    const float4* res4  = (const float4*)d_in[1];  // (16, 16384, 4) f32
    const float4* bias4 = (const float4*)d_in[2];  // (65536,) f32
    float* y = (float*)d_out;                      // (16, 65536) f32

    const size_t part_bytes = (size_t)NB * GPB * DIM * 4;   // 64 MB

    if (ws_size >= part_bytes) {
        float* part = (float*)d_ws;
        f1_gen_reduce<<<NB * GPB, 1024, 0, stream>>>(x, res4, part);
        f2_final<<<(NB * DIM / 4) / 256, 256, 0, stream>>>(
            (const f32x4*)part, (const f32x4*)d_in[2], (f32x4*)y);
    } else {
        // ws too small for partials: round-3 atomic path
        init_bias_kernel<<<(NB * DIM / 4) / 256, 256, 0, stream>>>(bias4, (float4*)y);
        hyper_scatter<<<(NB * NK) / 256, 256, 0, stream>>>(x, res4, y);
    }
}

// Round 8
// 175.761 us; speedup vs baseline: 3.0005x; 1.0022x over previous
//
#include <hip/hip_runtime.h>
#include <stdint.h>
#include <math.h>

// Problem constants (from reference)
#define NB 16
#define NK 16384
#define NADD 32
#define NP 36            // 2^RANK + ADD = 4 + 32
#define DIM 65536        // IN_DIM == OUT_DIM
#define NCH 4            // output chunks per batch row
#define CHW 16384        // chunk width (floats) -> 64 KB LDS accumulator
#define GPB 16           // point-groups per batch row (NK / 1024)

// native vector type for nontemporal builtins (HIP_vector_type rejected)
typedef float f32x4 __attribute__((ext_vector_type(4)));

__device__ __forceinline__ uint32_t rotl32(uint32_t x, uint32_t r) {
    return (x << r) | (x >> (32u - r));
}

// Threefry-2x32 (20 rounds), key = (0, 42); partitionable mode: ctr=(0,idx),
// bits = out0 ^ out1. CONFIRMED bit-correct (rounds 1-7).
__device__ __forceinline__ uint32_t tf_bits(uint32_t idx) {
    const uint32_t K1 = 42u;
    const uint32_t K2 = 0x1BD11BDAu ^ 42u;
    uint32_t x0 = 0u;
    uint32_t x1 = idx + K1;
#define TF_ROUND(r) { x0 += x1; x1 = rotl32(x1, r); x1 ^= x0; }
#define TF_G(a,b,c,d) TF_ROUND(a) TF_ROUND(b) TF_ROUND(c) TF_ROUND(d)
    TF_G(13,15,26,6)   x0 += K1;  x1 += K2 + 1u;
    TF_G(17,29,16,24)  x0 += K2;  x1 += 2u;
    TF_G(13,15,26,6)              x1 += K1 + 3u;
    TF_G(17,29,16,24)  x0 += K1;  x1 += K2 + 4u;
    TF_G(13,15,26,6)   x0 += K2;  x1 += 5u;
#undef TF_G
#undef TF_ROUND
    return x0 ^ x1;
}

// Bit-exact XLA:CPU f32 exp (Cephes/Eigen pexp), strict per-op f32 rounding,
// no FMA contraction. CONFIRMED: rounds 3-7 passed with absmax 7.8e-3.
__device__ __forceinline__ float xla_expf(float x0) {
    float x = fminf(fmaxf(x0, -88.3762626647949f), 88.3762626647950f);
    const float fx = floorf(__fadd_rn(__fmul_rn(x, 1.44269504088896341f), 0.5f));
    const float tmp = __fmul_rn(fx, 0.693359375f);
    float z = __fmul_rn(fx, -2.12194440e-4f);
    float r = __fsub_rn(x, tmp);
    r = __fsub_rn(r, z);
    z = __fmul_rn(r, r);
    float y = 1.9875691500E-4f;
    y = __fadd_rn(__fmul_rn(y, r), 1.3981999507E-3f);
    y = __fadd_rn(__fmul_rn(y, r), 8.3334519073E-3f);
    y = __fadd_rn(__fmul_rn(y, r), 4.1665795894E-2f);
    y = __fadd_rn(__fmul_rn(y, r), 1.6666665459E-1f);
    y = __fadd_rn(__fmul_rn(y, r), 5.0000001201E-1f);
    y = __fadd_rn(__fmul_rn(y, z), r);
    y = __fadd_rn(y, 1.0f);
    const int n = (int)fx;
    const float p2n = __uint_as_float((uint32_t)(n + 127) << 23);
    return fmaxf(__fmul_rn(y, p2n), x0);
}

// Shared generation: fills packed[36] ((out<<16)|in) and w[36] (normalized
// weight scale*prop). Identical arithmetic to the round-3..7 passing kernels.
__device__ __forceinline__ void gen_point(const float4 r, uint32_t tid,
                                          uint32_t* packed, float* w) {
    const float e0 = xla_expf(-r.x);
    const float e1 = xla_expf(-r.y);
    const float s0 = __fdiv_rn(1.0f, __fadd_rn(1.0f, e0));
    const float s1 = __fdiv_rn(1.0f, __fadd_rn(1.0f, e1));
    const float m0 = __fmul_rn(s0, 65535.0f);
    const float m1 = __fmul_rn(s1, 65535.0f);

    const float a2 = r.z + 2.0f;
    const float sp = fmaxf(a2, 0.0f) + log1pf(expf(-fabsf(a2)));
    const float sigma = (sp + 1e-6f) * 65536.0f;
    const float val = r.w;

    const float f0 = floorf(m0), c0 = ceilf(m0);
    const float f1 = floorf(m1), c1 = ceilf(m1);
    {
        const float cd0[4] = {f0, f0, c0, c0};
        const float cd1[4] = {f1, c1, f1, c1};
        #pragma unroll
        for (int p = 0; p < 4; ++p) {
            const float z0 = (cd0[p] - m0) / sigma;
            const float z1 = (cd1[p] - m1) / sigma;
            w[p] = expf(-0.5f * (z0*z0 + z1*z1));
            packed[p] = ((uint32_t)(int)cd0[p] << 16) | (uint32_t)(int)cd1[p];
        }
    }
    const float ONE_MEPS = (float)(1.0 - 1e-6);
    const uint32_t base = tid * 64u;
    #pragma unroll
    for (int a = 0; a < NADD; ++a) {
        const uint32_t bb0 = tf_bits(base + 2u*(uint32_t)a);
        const uint32_t bb1 = tf_bits(base + 2u*(uint32_t)a + 1u);
        const float u0 = __fmul_rn(__uint_as_float((bb0 >> 9) | 0x3f800000u) - 1.0f, ONE_MEPS);
        const float u1 = __fmul_rn(__uint_as_float((bb1 >> 9) | 0x3f800000u) - 1.0f, ONE_MEPS);
        const float s0f = floorf(__fmul_rn(u0, 65536.0f));
        const float s1f = floorf(__fmul_rn(u1, 65536.0f));
        const float z0 = (s0f - m0) / sigma;
        const float z1 = (s1f - m1) / sigma;
        w[4 + a] = expf(-0.5f * (z0*z0 + z1*z1));
        packed[4 + a] = ((uint32_t)(int)s0f << 16) | (uint32_t)(int)s1f;
    }
    float denom = 0.0f;
    #pragma unroll
    for (int p = 0; p < NP; ++p) denom += w[p] + 1e-6f;
    const float scale = val / denom;
    #pragma unroll
    for (int p = 0; p < NP; ++p) w[p] *= scale;
}

// ---------------- fast path: fused gen+reduce, then coalesced sum ----------

// F1: 256 blocks x 1024 threads, exactly 1 block/CU (grid == CU count).
// __launch_bounds__(1024, 4): 4 waves/EU = 16 waves/CU = this one block ->
// VGPR cap 128 (not 64). Round-7 post-mortem: compiler capped at 64 VGPR for
// a 2-blocks/CU occupancy the grid never uses, spilling the 72-register
// candidate state to scratch and re-loading it every pass (the 60% stall).
__global__ __launch_bounds__(1024, 4) void f1_gen_reduce(
    const float*  __restrict__ x,     // (NB, DIM)
    const float4* __restrict__ res4,  // (NB, NK, 4)
    float* __restrict__ part)         // [NB*GPB][DIM]
{
    __shared__ float acc[CHW];        // 64 KB
    f32x4* const acc4 = reinterpret_cast<f32x4*>(acc);
    const int blk = blockIdx.x;       // = b*GPB + g
    const int b = blk >> 4;
    const uint32_t tid = (uint32_t)blk * 1024u + threadIdx.x;  // global point id

    uint32_t packed[NP];
    float    w[NP];
    gen_point(res4[tid], tid, packed, w);

    // fold gather: w[p] <- w[p] * x[b, in_idx]; then repack to scatter key.
    const float* __restrict__ xrow = x + ((size_t)b << 16);
    #pragma unroll
    for (int p = 0; p < NP; ++p) {
        w[p] *= xrow[packed[p] & 0xFFFFu];
        packed[p] = (packed[p] >> 16) << 2;   // sc = out*4
    }

    float* __restrict__ dst = part + ((size_t)blk << 16);
    #pragma unroll 1
    for (uint32_t c = 0; c < NCH; ++c) {
        // vectorized zero: 4096 f32x4 / 1024 threads = 4 iters
        #pragma unroll
        for (int j = 0; j < 4; ++j)
            acc4[j * 1024 + threadIdx.x] = (f32x4)(0.0f);
        __syncthreads();
        #pragma unroll
        for (int p = 0; p < NP; ++p) {
            if ((packed[p] >> 16) == c)
                atomicAdd(&acc[(packed[p] & 0xFFFFu) >> 2], w[p]);
        }
        __syncthreads();
        // vectorized nontemporal store (64 MB stream, read once by f2)
        f32x4* __restrict__ dst4 = reinterpret_cast<f32x4*>(dst + c * CHW);
        #pragma unroll
        for (int j = 0; j < 4; ++j)
            __builtin_nontemporal_store(acc4[j * 1024 + threadIdx.x],
                                        &dst4[j * 1024 + threadIdx.x]);
        __syncthreads();   // protect acc from next pass's zeroing
    }
}

// F2: y = bias + sum_g part[(b*GPB+g)]; fully coalesced f32x4, nontemporal.
__global__ __launch_bounds__(256) void f2_final(
    const f32x4* __restrict__ part4,
    const f32x4* __restrict__ bias4,
    f32x4* __restrict__ y4)
{
    const int i = blockIdx.x * 256 + threadIdx.x;  // [0, NB*DIM/4)
    const int o4 = i & 16383;
    const int b = i >> 14;
    f32x4 s = bias4[o4];
    #pragma unroll
    for (int g = 0; g < GPB; ++g) {
        const f32x4 p = __builtin_nontemporal_load(
            &part4[(((size_t)(b * GPB + g)) << 14) + o4]);
        s += p;
    }
    __builtin_nontemporal_store(s, &y4[i]);
}

// ---------------- fallback path (round-3 passing kernel) ----------------

__global__ __launch_bounds__(256) void init_bias_kernel(
    const float4* __restrict__ bias4, float4* __restrict__ y4)
{
    const int i = blockIdx.x * 256 + threadIdx.x;
    y4[i] = bias4[i & 16383];
}

__global__ __launch_bounds__(256) void hyper_scatter(
    const float*  __restrict__ x,
    const float4* __restrict__ res4,
    float*        __restrict__ y)
{
    const int tid = blockIdx.x * 256 + threadIdx.x;
    const int b = tid >> 14;
    uint32_t packed[NP];
    float    w[NP];
    gen_point(res4[tid], (uint32_t)tid, packed, w);
    const float* __restrict__ xrow = x + ((size_t)b << 16);
    float*       __restrict__ yrow = y + ((size_t)b << 16);
    #pragma unroll
    for (int p = 0; p < NP; ++p) {
        const float xv = xrow[packed[p] & 0xFFFFu];
        unsafeAtomicAdd(&yrow[packed[p] >> 16], w[p] * xv);
    }
}

extern "C" void kernel_launch(void* const* d_in, const int* in_sizes, int n_in,
                              void* d_out, int out_size, void* d_ws, size_t ws_size,
                              hipStream_t stream) {
    const float*  x     = (const float*)d_in[0];   // (16, 65536) f32
    const float4* res4  = (const float4*)d_in[1];  // (16, 16384, 4) f32
    const float4* bias4 = (const float4*)d_in[2];  // (65536,) f32
    float* y = (float*)d_out;                      // (16, 65536) f32

    const size_t part_bytes = (size_t)NB * GPB * DIM * 4;   // 64 MB

    if (ws_size >= part_bytes) {
        float* part = (float*)d_ws;
        f1_gen_reduce<<<NB * GPB, 1024, 0, stream>>>(x, res4, part);
        f2_final<<<(NB * DIM / 4) / 256, 256, 0, stream>>>(
            (const f32x4*)part, (const f32x4*)d_in[2], (f32x4*)y);
    } else {
        // ws too small for partials: round-3 atomic path
        init_bias_kernel<<<(NB * DIM / 4) / 256, 256, 0, stream>>>(bias4, (float4*)y);
        hyper_scatter<<<(NB * NK) / 256, 256, 0, stream>>>(x, res4, y);
    }
}

// Round 10
// 174.138 us; speedup vs baseline: 3.0285x; 1.0093x over previous
//
#include <hip/hip_runtime.h>
#include <stdint.h>
#include <math.h>

// Problem constants (from reference)
#define NB 16
#define NK 16384
#define NADD 32
#define NP 36            // 2^RANK + ADD = 4 + 32
#define DIM 65536        // IN_DIM == OUT_DIM

// primary geometry: 512 blocks x 512 threads, 2 blocks/CU co-resident
#define TPB 512          // threads per block (8 waves)
#define GPB2 32          // groups per batch row (NK / TPB)
#define NCH2 8           // output chunks per batch row
#define CHW2 8192        // chunk width (floats) -> 32 KB LDS accumulator

// round-8 geometry (middle path): 256 blocks x 1024 threads
#define GPB 16
#define NCH 4
#define CHW 16384

// native vector type for nontemporal builtins (HIP_vector_type rejected)
typedef float f32x4 __attribute__((ext_vector_type(4)));

__device__ __forceinline__ uint32_t rotl32(uint32_t x, uint32_t r) {
    return (x << r) | (x >> (32u - r));
}

// Threefry-2x32 (20 rounds), key = (0, 42); partitionable mode: ctr=(0,idx),
// bits = out0 ^ out1. CONFIRMED bit-correct (rounds 1-8).
__device__ __forceinline__ uint32_t tf_bits(uint32_t idx) {
    const uint32_t K1 = 42u;
    const uint32_t K2 = 0x1BD11BDAu ^ 42u;
    uint32_t x0 = 0u;
    uint32_t x1 = idx + K1;
#define TF_ROUND(r) { x0 += x1; x1 = rotl32(x1, r); x1 ^= x0; }
#define TF_G(a,b,c,d) TF_ROUND(a) TF_ROUND(b) TF_ROUND(c) TF_ROUND(d)
    TF_G(13,15,26,6)   x0 += K1;  x1 += K2 + 1u;
    TF_G(17,29,16,24)  x0 += K2;  x1 += 2u;
    TF_G(13,15,26,6)              x1 += K1 + 3u;
    TF_G(17,29,16,24)  x0 += K1;  x1 += K2 + 4u;
    TF_G(13,15,26,6)   x0 += K2;  x1 += 5u;
#undef TF_G
#undef TF_ROUND
    return x0 ^ x1;
}

// Bit-exact XLA:CPU f32 exp (Cephes/Eigen pexp), strict per-op f32 rounding,
// no FMA contraction. CONFIRMED: rounds 3-8 passed with absmax 7.8e-3.
__device__ __forceinline__ float xla_expf(float x0) {
    float x = fminf(fmaxf(x0, -88.3762626647949f), 88.3762626647950f);
    const float fx = floorf(__fadd_rn(__fmul_rn(x, 1.44269504088896341f), 0.5f));
    const float tmp = __fmul_rn(fx, 0.693359375f);
    float z = __fmul_rn(fx, -2.12194440e-4f);
    float r = __fsub_rn(x, tmp);
    r = __fsub_rn(r, z);
    z = __fmul_rn(r, r);
    float y = 1.9875691500E-4f;
    y = __fadd_rn(__fmul_rn(y, r), 1.3981999507E-3f);
    y = __fadd_rn(__fmul_rn(y, r), 8.3334519073E-3f);
    y = __fadd_rn(__fmul_rn(y, r), 4.1665795894E-2f);
    y = __fadd_rn(__fmul_rn(y, r), 1.6666665459E-1f);
    y = __fadd_rn(__fmul_rn(y, r), 5.0000001201E-1f);
    y = __fadd_rn(__fmul_rn(y, z), r);
    y = __fadd_rn(y, 1.0f);
    const int n = (int)fx;
    const float p2n = __uint_as_float((uint32_t)(n + 127) << 23);
    return fmaxf(__fmul_rn(y, p2n), x0);
}

// Shared generation: fills packed[36] ((out<<16)|in) and w[36] (normalized
// weight scale*prop). Identical arithmetic to the round-3..8 passing kernels.
__device__ __forceinline__ void gen_point(const float4 r, uint32_t tid,
                                          uint32_t* packed, float* w) {
    const float e0 = xla_expf(-r.x);
    const float e1 = xla_expf(-r.y);
    const float s0 = __fdiv_rn(1.0f, __fadd_rn(1.0f, e0));
    const float s1 = __fdiv_rn(1.0f, __fadd_rn(1.0f, e1));
    const float m0 = __fmul_rn(s0, 65535.0f);
    const float m1 = __fmul_rn(s1, 65535.0f);

    const float a2 = r.z + 2.0f;
    const float sp = fmaxf(a2, 0.0f) + log1pf(expf(-fabsf(a2)));
    const float sigma = (sp + 1e-6f) * 65536.0f;
    const float val = r.w;

    const float f0 = floorf(m0), c0 = ceilf(m0);
    const float f1 = floorf(m1), c1 = ceilf(m1);
    {
        const float cd0[4] = {f0, f0, c0, c0};
        const float cd1[4] = {f1, c1, f1, c1};
        #pragma unroll
        for (int p = 0; p < 4; ++p) {
            const float z0 = (cd0[p] - m0) / sigma;
            const float z1 = (cd1[p] - m1) / sigma;
            w[p] = expf(-0.5f * (z0*z0 + z1*z1));
            packed[p] = ((uint32_t)(int)cd0[p] << 16) | (uint32_t)(int)cd1[p];
        }
    }
    const float ONE_MEPS = (float)(1.0 - 1e-6);
    const uint32_t base = tid * 64u;
    #pragma unroll
    for (int a = 0; a < NADD; ++a) {
        const uint32_t bb0 = tf_bits(base + 2u*(uint32_t)a);
        const uint32_t bb1 = tf_bits(base + 2u*(uint32_t)a + 1u);
        const float u0 = __fmul_rn(__uint_as_float((bb0 >> 9) | 0x3f800000u) - 1.0f, ONE_MEPS);
        const float u1 = __fmul_rn(__uint_as_float((bb1 >> 9) | 0x3f800000u) - 1.0f, ONE_MEPS);
        const float s0f = floorf(__fmul_rn(u0, 65536.0f));
        const float s1f = floorf(__fmul_rn(u1, 65536.0f));
        const float z0 = (s0f - m0) / sigma;
        const float z1 = (s1f - m1) / sigma;
        w[4 + a] = expf(-0.5f * (z0*z0 + z1*z1));
        packed[4 + a] = ((uint32_t)(int)s0f << 16) | (uint32_t)(int)s1f;
    }
    float denom = 0.0f;
    #pragma unroll
    for (int p = 0; p < NP; ++p) denom += w[p] + 1e-6f;
    const float scale = val / denom;
    #pragma unroll
    for (int p = 0; p < NP; ++p) w[p] *= scale;
}

// ------------- primary: 512x512, f32 partials (128 MB), 2 blocks/CU -------

__global__ __launch_bounds__(TPB, 4) void f1_gen_reduce_512(
    const float*  __restrict__ x,     // (NB, DIM)
    const float4* __restrict__ res4,  // (NB, NK, 4)
    float* __restrict__ part)         // [NB*GPB2][DIM] f32
{
    __shared__ float acc[CHW2];       // 32 KB -> 2 blocks/CU
    f32x4* const acc4 = reinterpret_cast<f32x4*>(acc);
    const int blk = blockIdx.x;
    const uint32_t tid = (uint32_t)blk * TPB + threadIdx.x;  // global point id
    const int b = (int)(tid >> 14);

    uint32_t packed[NP];
    float    w[NP];
    gen_point(res4[tid], tid, packed, w);

    const float* __restrict__ xrow = x + ((size_t)b << 16);
    #pragma unroll
    for (int p = 0; p < NP; ++p) {
        w[p] *= xrow[packed[p] & 0xFFFFu];
        packed[p] = packed[p] >> 16;            // out in [0, 65536)
    }

    float* __restrict__ dst = part + ((size_t)blk << 16);  // row = 65536 f32
    #pragma unroll 1
    for (uint32_t c = 0; c < NCH2; ++c) {
        // zero: 2048 f32x4 / 512 threads = 4 iters
        #pragma unroll
        for (int j = 0; j < 4; ++j)
            acc4[j * TPB + threadIdx.x] = (f32x4)(0.0f);
        __syncthreads();
        #pragma unroll
        for (int p = 0; p < NP; ++p) {
            if ((packed[p] >> 13) == c)
                atomicAdd(&acc[packed[p] & (CHW2 - 1)], w[p]);
        }
        __syncthreads();
        // nontemporal store: chunk = 8192 f32 = 2048 f32x4
        f32x4* __restrict__ dst4 = reinterpret_cast<f32x4*>(dst + c * CHW2);
        #pragma unroll
        for (int j = 0; j < 4; ++j)
            __builtin_nontemporal_store(acc4[j * TPB + threadIdx.x],
                                        &dst4[j * TPB + threadIdx.x]);
        __syncthreads();
    }
}

__global__ __launch_bounds__(256) void f2_final_32(
    const f32x4* __restrict__ part4,  // [NB*GPB2][DIM/4]
    const f32x4* __restrict__ bias4,
    f32x4* __restrict__ y4)
{
    const int i = blockIdx.x * 256 + threadIdx.x;  // [0, NB*DIM/4)
    const int o4 = i & 16383;
    const int b = i >> 14;
    f32x4 s = bias4[o4];
    #pragma unroll
    for (int g = 0; g < GPB2; ++g) {
        const f32x4 p = __builtin_nontemporal_load(
            &part4[(((size_t)(b * GPB2 + g)) << 14) + o4]);
        s += p;
    }
    __builtin_nontemporal_store(s, &y4[i]);
}

// ------------- middle: round-8 proven path (256x1024, f32, 64 MB) ---------

__global__ __launch_bounds__(1024, 4) void f1_gen_reduce_1024(
    const float*  __restrict__ x,
    const float4* __restrict__ res4,
    float* __restrict__ part)         // [NB*GPB][DIM]
{
    __shared__ float acc[CHW];        // 64 KB
    f32x4* const acc4 = reinterpret_cast<f32x4*>(acc);
    const int blk = blockIdx.x;
    const int b = blk >> 4;
    const uint32_t tid = (uint32_t)blk * 1024u + threadIdx.x;

    uint32_t packed[NP];
    float    w[NP];
    gen_point(res4[tid], tid, packed, w);

    const float* __restrict__ xrow = x + ((size_t)b << 16);
    #pragma unroll
    for (int p = 0; p < NP; ++p) {
        w[p] *= xrow[packed[p] & 0xFFFFu];
        packed[p] = packed[p] >> 16;
    }

    float* __restrict__ dst = part + ((size_t)blk << 16);
    #pragma unroll 1
    for (uint32_t c = 0; c < NCH; ++c) {
        #pragma unroll
        for (int j = 0; j < 4; ++j)
            acc4[j * 1024 + threadIdx.x] = (f32x4)(0.0f);
        __syncthreads();
        #pragma unroll
        for (int p = 0; p < NP; ++p) {
            if ((packed[p] >> 14) == c)
                atomicAdd(&acc[packed[p] & (CHW - 1)], w[p]);
        }
        __syncthreads();
        f32x4* __restrict__ dst4 = reinterpret_cast<f32x4*>(dst + c * CHW);
        #pragma unroll
        for (int j = 0; j < 4; ++j)
            __builtin_nontemporal_store(acc4[j * 1024 + threadIdx.x],
                                        &dst4[j * 1024 + threadIdx.x]);
        __syncthreads();
    }
}

__global__ __launch_bounds__(256) void f2_final_16(
    const f32x4* __restrict__ part4,
    const f32x4* __restrict__ bias4,
    f32x4* __restrict__ y4)
{
    const int i = blockIdx.x * 256 + threadIdx.x;
    const int o4 = i & 16383;
    const int b = i >> 14;
    f32x4 s = bias4[o4];
    #pragma unroll
    for (int g = 0; g < GPB; ++g) {
        const f32x4 p = __builtin_nontemporal_load(
            &part4[(((size_t)(b * GPB + g)) << 14) + o4]);
        s += p;
    }
    __builtin_nontemporal_store(s, &y4[i]);
}

// ---------------- fallback path (round-3 passing kernel) ----------------

__global__ __launch_bounds__(256) void init_bias_kernel(
    const float4* __restrict__ bias4, float4* __restrict__ y4)
{
    const int i = blockIdx.x * 256 + threadIdx.x;
    y4[i] = bias4[i & 16383];
}

__global__ __launch_bounds__(256) void hyper_scatter(
    const float*  __restrict__ x,
    const float4* __restrict__ res4,
    float*        __restrict__ y)
{
    const int tid = blockIdx.x * 256 + threadIdx.x;
    const int b = tid >> 14;
    uint32_t packed[NP];
    float    w[NP];
    gen_point(res4[tid], (uint32_t)tid, packed, w);
    const float* __restrict__ xrow = x + ((size_t)b << 16);
    float*       __restrict__ yrow = y + ((size_t)b << 16);
    #pragma unroll
    for (int p = 0; p < NP; ++p) {
        const float xv = xrow[packed[p] & 0xFFFFu];
        unsafeAtomicAdd(&yrow[packed[p] >> 16], w[p] * xv);
    }
}

extern "C" void kernel_launch(void* const* d_in, const int* in_sizes, int n_in,
                              void* d_out, int out_size, void* d_ws, size_t ws_size,
                              hipStream_t stream) {
    const float*  x     = (const float*)d_in[0];   // (16, 65536) f32
    const float4* res4  = (const float4*)d_in[1];  // (16, 16384, 4) f32
    const float4* bias4 = (const float4*)d_in[2];  // (65536,) f32
    float* y = (float*)d_out;                      // (16, 65536) f32

    const size_t need512 = (size_t)NB * GPB2 * DIM * 4;   // 128 MB
    const size_t need256 = (size_t)NB * GPB  * DIM * 4;   // 64 MB

    if (ws_size >= need512) {
        float* part = (float*)d_ws;
        f1_gen_reduce_512<<<NB * GPB2, TPB, 0, stream>>>(x, res4, part);
        f2_final_32<<<(NB * DIM / 4) / 256, 256, 0, stream>>>(
            (const f32x4*)part, (const f32x4*)bias4, (f32x4*)y);
    } else if (ws_size >= need256) {
        float* part = (float*)d_ws;
        f1_gen_reduce_1024<<<NB * GPB, 1024, 0, stream>>>(x, res4, part);
        f2_final_16<<<(NB * DIM / 4) / 256, 256, 0, stream>>>(
            (const f32x4*)part, (const f32x4*)bias4, (f32x4*)y);
    } else {
        init_bias_kernel<<<(NB * DIM / 4) / 256, 256, 0, stream>>>(bias4, (float4*)y);
        hyper_scatter<<<(NB * NK) / 256, 256, 0, stream>>>(x, res4, y);
    }
}